// Round 20
// baseline (157.671 us; speedup 1.0000x reference)
//
#include <hip/hip_runtime.h>

// QSScan: quantized selective scan (Mamba-style), int8-in-int32 + scalar scales.
// Chunked parallel linear recurrence, serial-in-thread, LDS-transpose-staged I/O.
//   phase1: thread=(scan,chunk): local scan from 0 over LC=64 -> X_end[16], S=sum(delta)
//   combine: thread=(scan,n): fold 32 chunks -> true init per chunk
//   phase2: thread=(scan,chunk): rerun from true init -> y=(x.C)*C_s+D*u, silu(z) gate
// R20 vs R19 (phase2 98us, WRITE fixed at 89MB, occupancy ~36% = LDS-capped
// 4 blocks/CU at 38.4KB -> latency-bound):
//   - T=16 sub-tiles: su/sd/sz 27.6->15.4KB, tB/tC 10.4->5.2KB => 20.6KB total
//     -> 7 blocks/CU (87% occupancy cap). 64B-segment loads = one L2 sector
//     (proven by R19's write-side 64B granularity) -> no read overfetch.
//   - ya[16] now spans the whole sub-tile: still one fully-dirty 64B sector
//     per burst (keeps R19's write fix)

#define LOG2E 1.44269504088896340736f
#define LN2F  0.69314718055994530942f

constexpr int BATCH = 2;
constexpr int DIM   = 4096;
constexpr int LSEQ  = 2048;
constexpr int NST   = 16;
constexpr int SCANS = BATCH * DIM;   // 8192
constexpr int K     = 32;            // chunks per scan
constexpr int LC    = LSEQ / K;      // 64 timesteps per chunk
constexpr int T     = 16;            // timesteps per staged sub-tile (64B of int32)
constexpr int NSUB  = LC / T;        // 4 sub-tiles per chunk
constexpr int CPB   = 2;             // chunks per block
constexpr int SPB   = 128;           // scans per block (256 threads = SPB x CPB)
constexpr int SCOLW = 5;             // words per staged col: 16B data + 4B pad
constexpr int BCHS  = 328;           // words per chunk in tB/tC: 16*20 + 8 pad

__device__ __forceinline__ float softplus_f(float x) {
    float e = __builtin_amdgcn_exp2f(x * LOG2E);
    return __builtin_amdgcn_logf(1.f + e) * LN2F;
}

__device__ __forceinline__ int pack8(int4 v) {   // values in [-127,127]: exact
    return (v.x & 255) | ((v.y & 255) << 8) | ((v.z & 255) << 16) | ((v.w & 255) << 24);
}

#define LOAD_A2()                                                              \
    float A2[NST];                                                             \
    {                                                                          \
        const int4* ap = (const int4*)(A_log + d * NST);                       \
        int4 a0 = ap[0], a1 = ap[1], a2 = ap[2], a3 = ap[3];                   \
        const int ai[NST] = {a0.x,a0.y,a0.z,a0.w, a1.x,a1.y,a1.z,a1.w,         \
                             a2.x,a2.y,a2.z,a2.w, a3.x,a3.y,a3.z,a3.w};        \
        _Pragma("unroll")                                                      \
        for (int n = 0; n < NST; ++n)                                          \
            A2[n] = -__builtin_amdgcn_exp2f((float)ai[n] * (A_s * LOG2E)) * LOG2E; \
    }

// advance 4 states (q-th quad) and accumulate y; keeps only 2 float4 live
#define STEP4(q, bt, ct)                                                       \
    {                                                                          \
        const float4 Bq = *(const float4*)((bt) + 4 * (q));                    \
        const float4 Cq = *(const float4*)((ct) + 4 * (q));                    \
        x[4*(q)+0] = __builtin_fmaf(__builtin_amdgcn_exp2f(A2[4*(q)+0] * delta), x[4*(q)+0], w * Bq.x); \
        y = __builtin_fmaf(x[4*(q)+0], Cq.x, y);                               \
        x[4*(q)+1] = __builtin_fmaf(__builtin_amdgcn_exp2f(A2[4*(q)+1] * delta), x[4*(q)+1], w * Bq.y); \
        y = __builtin_fmaf(x[4*(q)+1], Cq.y, y);                               \
        x[4*(q)+2] = __builtin_fmaf(__builtin_amdgcn_exp2f(A2[4*(q)+2] * delta), x[4*(q)+2], w * Bq.z); \
        y = __builtin_fmaf(x[4*(q)+2], Cq.z, y);                               \
        x[4*(q)+3] = __builtin_fmaf(__builtin_amdgcn_exp2f(A2[4*(q)+3] * delta), x[4*(q)+3], w * Bq.w); \
        y = __builtin_fmaf(x[4*(q)+3], Cq.w, y);                               \
    }

#define STEP4B(q, bt)                                                          \
    {                                                                          \
        const float4 Bq = *(const float4*)((bt) + 4 * (q));                    \
        x[4*(q)+0] = __builtin_fmaf(__builtin_amdgcn_exp2f(A2[4*(q)+0] * delta), x[4*(q)+0], w * Bq.x); \
        x[4*(q)+1] = __builtin_fmaf(__builtin_amdgcn_exp2f(A2[4*(q)+1] * delta), x[4*(q)+1], w * Bq.y); \
        x[4*(q)+2] = __builtin_fmaf(__builtin_amdgcn_exp2f(A2[4*(q)+2] * delta), x[4*(q)+2], w * Bq.z); \
        x[4*(q)+3] = __builtin_fmaf(__builtin_amdgcn_exp2f(A2[4*(q)+3] * delta), x[4*(q)+3], w * Bq.w); \
    }

// ---------------- Phase 1: per-chunk summaries (X_end, S) ----------------
__global__ __launch_bounds__(256, 4) void qs_phase1(
    const int* __restrict__ u,  const int* __restrict__ dt,
    const int* __restrict__ Bm, const int* __restrict__ A_log,
    const int* __restrict__ dt_bias,
    const float* __restrict__ u_sp, const float* __restrict__ dt_sp,
    const float* __restrict__ A_sp, const float* __restrict__ B_sp,
    const float* __restrict__ dtb_sp,
    float* __restrict__ Sbuf, float* __restrict__ Xbuf)
{
    const int tid = threadIdx.x;
    const int cg  = blockIdx.x >> 6;           // chunk-group 0..15
    const int sg  = blockIdx.x & 63;           // scan-group 0..63
    const int scan  = sg * SPB + (tid & (SPB - 1));
    const int chunk = cg * CPB + (tid >> 7);
    const int d  = scan & (DIM - 1);
    const int bb = sg >> 5;                    // batch, uniform per block

    __shared__ int   su_i[256 * SCOLW];
    __shared__ int   sd_i[256 * SCOLW];
    __shared__ float tB[CPB * BCHS];

    const float u_s = *u_sp, dt_s = *dt_sp, A_s = *A_sp, B_s = *B_sp, dtb_s = *dtb_sp;
    LOAD_A2();
    const float dtb = (float)dt_bias[d] * dtb_s;

    const int lc4 = tid >> 2, lq4 = tid & 3;   // 4 lanes cover one col's 64B sub-tile
    const int in0 = sg * SPB * LSEQ + cg * (CPB * LC);
    const int kB  = tid & 15, nB0 = tid >> 4;  // B-stage role (16k x 16n)
    const int bcol  = tid * (SCOLW * 4);       // own column byte offset
    const int tbase = (tid >> 7) * BCHS;       // own chunk's tile base (wave-uniform)

    float x[NST];
#pragma unroll
    for (int n = 0; n < NST; ++n) x[n] = 0.f;
    float S = 0.f;

    for (int st = 0; st < NSUB; ++st) {
        const int c0 = st * T;
#pragma unroll
        for (int p = 0; p < 4; ++p) {          // 256 cols x 4 int4-segments
            const int col = p * 64 + lc4;
            const int ga  = in0 + (col & (SPB - 1)) * LSEQ + (col >> 7) * LC + c0 + 4 * lq4;
            su_i[col * SCOLW + lq4] = pack8(*(const int4*)(u  + ga));
            sd_i[col * SCOLW + lq4] = pack8(*(const int4*)(dt + ga));
        }
#pragma unroll
        for (int j = 0; j < CPB; ++j) {
            const int gr = (bb * NST + nB0) * LSEQ + cg * (CPB * LC) + j * LC + c0 + kB;
            tB[j * BCHS + kB * 20 + nB0] = (float)Bm[gr];
        }
        __syncthreads();

        const signed char* suc = (const signed char*)su_i;
        const signed char* sdc = (const signed char*)sd_i;
#pragma unroll 4
        for (int k = 0; k < T; ++k) {
            const float uf    = (float)suc[bcol + k] * u_s;
            const float delta = softplus_f((float)sdc[bcol + k] * dt_s + dtb);
            const float w     = delta * uf * B_s;
            S += delta;
            const float* bt = &tB[tbase + k * 20];
            STEP4B(0, bt); STEP4B(1, bt); STEP4B(2, bt); STEP4B(3, bt);
        }
        __syncthreads();
    }

    Sbuf[chunk * SCANS + scan] = S;
    float4* Xo = (float4*)(Xbuf + (chunk * SCANS + scan) * NST);
#pragma unroll
    for (int q = 0; q < 4; ++q)
        Xo[q] = make_float4(x[4*q], x[4*q+1], x[4*q+2], x[4*q+3]);
}

// ---------------- Combine: fold summaries, write init states in-place ----------------
__global__ __launch_bounds__(256) void qs_combine(
    const int* __restrict__ A_log, const float* __restrict__ A_sp,
    const float* __restrict__ Sbuf, float* __restrict__ Xbuf)
{
    const int idx  = blockIdx.x * 256 + threadIdx.x;   // flat (scan, n)
    const int scan = idx >> 4, n = idx & 15;
    const int d    = scan & (DIM - 1);
    const float A2 = -__builtin_amdgcn_exp2f(
        (float)A_log[d * NST + n] * ((*A_sp) * LOG2E)) * LOG2E;
    float x = 0.f;
#pragma unroll
    for (int c = 0; c < K; ++c) {
        const int off = c * (SCANS * NST) + idx;
        const float Xe = Xbuf[off];
        const float P  = __builtin_amdgcn_exp2f(A2 * Sbuf[c * SCANS + scan]);
        Xbuf[off] = x;                                  // init state for chunk c
        x = __builtin_fmaf(P, x, Xe);
    }
}

// ---------------- Phase 2: rerun with true init, emit output ----------------
__global__ __launch_bounds__(256, 4) void qs_phase2(
    const int* __restrict__ u,  const int* __restrict__ dt,
    const int* __restrict__ Bm, const int* __restrict__ Cm,
    const int* __restrict__ z,  const int* __restrict__ A_log,
    const int* __restrict__ Dv, const int* __restrict__ dt_bias,
    const float* __restrict__ u_sp,  const float* __restrict__ dt_sp,
    const float* __restrict__ A_sp,  const float* __restrict__ B_sp,
    const float* __restrict__ C_sp,  const float* __restrict__ z_sp,
    const float* __restrict__ D_sp,  const float* __restrict__ dtb_sp,
    const float* __restrict__ XI, float* __restrict__ out)
{
    const int tid = threadIdx.x;
    const int cg  = blockIdx.x >> 6;
    const int sg  = blockIdx.x & 63;
    const int scan  = sg * SPB + (tid & (SPB - 1));
    const int chunk = cg * CPB + (tid >> 7);
    const int d  = scan & (DIM - 1);
    const int bb = sg >> 5;

    __shared__ int   su_i[256 * SCOLW];
    __shared__ int   sd_i[256 * SCOLW];
    __shared__ int   sz_i[256 * SCOLW];
    __shared__ float tB[CPB * BCHS];
    __shared__ float tC[CPB * BCHS];

    const float u_s = *u_sp, dt_s = *dt_sp, A_s = *A_sp, B_s = *B_sp;
    const float C_s = *C_sp, z_s  = *z_sp,  D_s = *D_sp, dtb_s = *dtb_sp;
    LOAD_A2();
    const float dtb = (float)dt_bias[d] * dtb_s;
    const float Dd  = (float)Dv[d] * D_s;

    float x[NST];
    {
        const float4* xi = (const float4*)(XI + (chunk * SCANS + scan) * NST);
        const float4 x0 = xi[0], x1 = xi[1], x2 = xi[2], x3 = xi[3];
        x[0]=x0.x; x[1]=x0.y; x[2]=x0.z; x[3]=x0.w;
        x[4]=x1.x; x[5]=x1.y; x[6]=x1.z; x[7]=x1.w;
        x[8]=x2.x; x[9]=x2.y; x[10]=x2.z; x[11]=x2.w;
        x[12]=x3.x; x[13]=x3.y; x[14]=x3.z; x[15]=x3.w;
    }

    const int lc4 = tid >> 2, lq4 = tid & 3;
    const int in0 = sg * SPB * LSEQ + cg * (CPB * LC);
    const int kB  = tid & 15, nB0 = tid >> 4;
    const int bcol  = tid * (SCOLW * 4);
    const int tbase = (tid >> 7) * BCHS;
    const int ob = scan * LSEQ + chunk * LC;   // own output row-chunk base

    for (int st = 0; st < NSUB; ++st) {
        const int c0 = st * T;
#pragma unroll
        for (int p = 0; p < 4; ++p) {
            const int col = p * 64 + lc4;
            const int ga  = in0 + (col & (SPB - 1)) * LSEQ + (col >> 7) * LC + c0 + 4 * lq4;
            su_i[col * SCOLW + lq4] = pack8(*(const int4*)(u  + ga));
            sd_i[col * SCOLW + lq4] = pack8(*(const int4*)(dt + ga));
            sz_i[col * SCOLW + lq4] = pack8(*(const int4*)(z  + ga));
        }
#pragma unroll
        for (int j = 0; j < CPB; ++j) {
            const int gr = (bb * NST + nB0) * LSEQ + cg * (CPB * LC) + j * LC + c0 + kB;
            tB[j * BCHS + kB * 20 + nB0] = (float)Bm[gr];
            tC[j * BCHS + kB * 20 + nB0] = (float)Cm[gr];
        }
        __syncthreads();

        const signed char* suc = (const signed char*)su_i;
        const signed char* sdc = (const signed char*)sd_i;
        const signed char* szc = (const signed char*)sz_i;
        float ya[T];                           // one 64B sector, burst at sub-tile end
#pragma unroll 4
        for (int k = 0; k < T; ++k) {
            const float uf    = (float)suc[bcol + k] * u_s;
            const float delta = softplus_f((float)sdc[bcol + k] * dt_s + dtb);
            const float w     = delta * uf * B_s;
            const float zf    = (float)szc[bcol + k] * z_s;
            const float gate  = zf * __builtin_amdgcn_rcpf(
                                    1.f + __builtin_amdgcn_exp2f(-zf * LOG2E));
            const float* bt = &tB[tbase + k * 20];
            const float* ct = &tC[tbase + k * 20];
            float y = 0.f;
            STEP4(0, bt, ct); STEP4(1, bt, ct); STEP4(2, bt, ct); STEP4(3, bt, ct);
            ya[k] = __builtin_fmaf(y, C_s, Dd * uf) * gate;
        }
        {
            float* ob2 = out + ob + c0;        // 4 back-to-back float4 stores:
#pragma unroll                                 // one fully-dirty 64B sector
            for (int q = 0; q < 4; ++q)
                *(float4*)(ob2 + 4 * q) =
                    make_float4(ya[4*q], ya[4*q+1], ya[4*q+2], ya[4*q+3]);
        }
        __syncthreads();
    }
}

extern "C" void kernel_launch(void* const* d_in, const int* in_sizes, int n_in,
                              void* d_out, int out_size, void* d_ws, size_t ws_size,
                              hipStream_t stream) {
    const int* u   = (const int*)d_in[0];
    const int* dt  = (const int*)d_in[1];
    const int* Bm  = (const int*)d_in[2];
    const int* Cm  = (const int*)d_in[3];
    const int* z   = (const int*)d_in[4];
    const int* Al  = (const int*)d_in[5];
    const int* Dv  = (const int*)d_in[6];
    const int* dtb = (const int*)d_in[7];
    const float* u_sp = (const float*)d_in[8],  * dt_sp = (const float*)d_in[9];
    const float* A_sp = (const float*)d_in[10], * B_sp  = (const float*)d_in[11];
    const float* C_sp = (const float*)d_in[12], * z_sp  = (const float*)d_in[13];
    const float* D_sp = (const float*)d_in[14], * dtb_sp= (const float*)d_in[15];

    float* Xbuf = (float*)d_ws;                          // K*SCANS*NST f32 = 16.8 MiB
    float* Sbuf = Xbuf + (size_t)K * SCANS * NST;        // K*SCANS f32 = 1 MiB

    dim3 blk(256);
    // grid: 16 chunk-groups x 64 scan-groups = 1024 blocks
    qs_phase1<<<dim3(16 * 64), blk, 0, stream>>>(u, dt, Bm, Al, dtb,
        u_sp, dt_sp, A_sp, B_sp, dtb_sp, Sbuf, Xbuf);
    qs_combine<<<dim3(SCANS * NST / 256), blk, 0, stream>>>(Al, A_sp, Sbuf, Xbuf);
    qs_phase2<<<dim3(16 * 64), blk, 0, stream>>>(u, dt, Bm, Cm, z, Al, Dv, dtb,
        u_sp, dt_sp, A_sp, B_sp, C_sp, z_sp, D_sp, dtb_sp, Xbuf, (float*)d_out);
}

// Round 21
// 149.321 us; speedup vs baseline: 1.0559x; 1.0559x over previous
//
#include <hip/hip_runtime.h>

// QSScan: quantized selective scan (Mamba-style), int8-in-int32 + scalar scales.
// Chunked parallel linear recurrence, serial-in-thread, LDS-transpose-staged I/O.
//   phase1: thread=(scan,chunk): local scan from 0 over LC=32 -> X_end[16], S=sum(delta)
//   combine: thread=(scan,n): fold 64 chunks -> true init per chunk
//   phase2: thread=(scan,chunk): rerun from true init -> y=(x.C)*C_s+D*u, silu(z) gate
// R21 vs R20 (phase2 101us, WRITE ideal 67MB but FETCH 209MB=2x from half-line
// T=16 loads, and occupancy stuck at 37% because GRID (1024 blocks = 4/CU) was
// the binding cap, not LDS):
//   - K=64 chunks (LC=32), CPB=1, SPB=256: grid 2048 blocks = 8/CU available
//   - each col's chunk input = exactly one 128B line -> single stage per chunk,
//     full-line loads (FETCH back to ideal)
//   - combined u|dt|z staging buffer, 100B/col stride (gcd(25,32)=1, conflict-
//     free): LDS 30.7KB -> 5 blocks/CU (62.5% cap); phase1 20KB -> 8 blocks
//   - keep ya[16] 64B sector-burst stores (R19/R20's proven write fix)

#define LOG2E 1.44269504088896340736f
#define LN2F  0.69314718055994530942f

constexpr int BATCH = 2;
constexpr int DIM   = 4096;
constexpr int LSEQ  = 2048;
constexpr int NST   = 16;
constexpr int SCANS = BATCH * DIM;   // 8192
constexpr int K     = 64;            // chunks per scan
constexpr int LC    = LSEQ / K;      // 32 timesteps per chunk (= one 128B line)
constexpr int SPB   = 256;           // scans per block (CPB = 1 chunk per block)
constexpr int NSG   = SCANS / SPB;   // 32 scan-groups

__device__ __forceinline__ float softplus_f(float x) {
    float e = __builtin_amdgcn_exp2f(x * LOG2E);
    return __builtin_amdgcn_logf(1.f + e) * LN2F;
}

__device__ __forceinline__ int pack8(int4 v) {   // values in [-127,127]: exact
    return (v.x & 255) | ((v.y & 255) << 8) | ((v.z & 255) << 16) | ((v.w & 255) << 24);
}

#define LOAD_A2()                                                              \
    float A2[NST];                                                             \
    {                                                                          \
        const int4* ap = (const int4*)(A_log + d * NST);                       \
        int4 a0 = ap[0], a1 = ap[1], a2 = ap[2], a3 = ap[3];                   \
        const int ai[NST] = {a0.x,a0.y,a0.z,a0.w, a1.x,a1.y,a1.z,a1.w,         \
                             a2.x,a2.y,a2.z,a2.w, a3.x,a3.y,a3.z,a3.w};        \
        _Pragma("unroll")                                                      \
        for (int n = 0; n < NST; ++n)                                          \
            A2[n] = -__builtin_amdgcn_exp2f((float)ai[n] * (A_s * LOG2E)) * LOG2E; \
    }

// advance 4 states (q-th quad) and accumulate y; keeps only 2 float4 live
#define STEP4(q, bt, ct)                                                       \
    {                                                                          \
        const float4 Bq = *(const float4*)((bt) + 4 * (q));                    \
        const float4 Cq = *(const float4*)((ct) + 4 * (q));                    \
        x[4*(q)+0] = __builtin_fmaf(__builtin_amdgcn_exp2f(A2[4*(q)+0] * delta), x[4*(q)+0], w * Bq.x); \
        y = __builtin_fmaf(x[4*(q)+0], Cq.x, y);                               \
        x[4*(q)+1] = __builtin_fmaf(__builtin_amdgcn_exp2f(A2[4*(q)+1] * delta), x[4*(q)+1], w * Bq.y); \
        y = __builtin_fmaf(x[4*(q)+1], Cq.y, y);                               \
        x[4*(q)+2] = __builtin_fmaf(__builtin_amdgcn_exp2f(A2[4*(q)+2] * delta), x[4*(q)+2], w * Bq.z); \
        y = __builtin_fmaf(x[4*(q)+2], Cq.z, y);                               \
        x[4*(q)+3] = __builtin_fmaf(__builtin_amdgcn_exp2f(A2[4*(q)+3] * delta), x[4*(q)+3], w * Bq.w); \
        y = __builtin_fmaf(x[4*(q)+3], Cq.w, y);                               \
    }

#define STEP4B(q, bt)                                                          \
    {                                                                          \
        const float4 Bq = *(const float4*)((bt) + 4 * (q));                    \
        x[4*(q)+0] = __builtin_fmaf(__builtin_amdgcn_exp2f(A2[4*(q)+0] * delta), x[4*(q)+0], w * Bq.x); \
        x[4*(q)+1] = __builtin_fmaf(__builtin_amdgcn_exp2f(A2[4*(q)+1] * delta), x[4*(q)+1], w * Bq.y); \
        x[4*(q)+2] = __builtin_fmaf(__builtin_amdgcn_exp2f(A2[4*(q)+2] * delta), x[4*(q)+2], w * Bq.z); \
        x[4*(q)+3] = __builtin_fmaf(__builtin_amdgcn_exp2f(A2[4*(q)+3] * delta), x[4*(q)+3], w * Bq.w); \
    }

// ---------------- Phase 1: per-chunk summaries (X_end, S) ----------------
__global__ __launch_bounds__(256, 4) void qs_phase1(
    const int* __restrict__ u,  const int* __restrict__ dt,
    const int* __restrict__ Bm, const int* __restrict__ A_log,
    const int* __restrict__ dt_bias,
    const float* __restrict__ u_sp, const float* __restrict__ dt_sp,
    const float* __restrict__ A_sp, const float* __restrict__ B_sp,
    const float* __restrict__ dtb_sp,
    float* __restrict__ Sbuf, float* __restrict__ Xbuf)
{
    const int tid = threadIdx.x;
    const int cg  = blockIdx.x >> 5;           // chunk 0..63
    const int sg  = blockIdx.x & 31;           // scan-group 0..31
    const int scan = sg * SPB + tid;
    const int d  = scan & (DIM - 1);
    const int bb = sg >> 4;                    // batch, uniform per block

    // per col: u 8w | dt 8w | pad 1w  (stride 17 words, gcd(17,32)=1)
    __shared__ int   sud[256 * 17];
    __shared__ float tB[LC * 20];

    const float u_s = *u_sp, dt_s = *dt_sp, A_s = *A_sp, B_s = *B_sp, dtb_s = *dtb_sp;
    LOAD_A2();
    const float dtb = (float)dt_bias[d] * dtb_s;

    const int lc8 = tid >> 3, lo8 = tid & 7;   // 8 lanes cover one col's 128B line
    const int in0 = sg * SPB * LSEQ + cg * LC;
    const int kB  = tid & 31, nB0 = tid >> 5;  // B-stage role (32k x 8n x 2)
    const int bcol = tid * 68;                 // own column byte offset

    // stage the whole chunk: each col = one full 128B line
#pragma unroll
    for (int p = 0; p < 8; ++p) {
        const int col = p * 32 + lc8;
        const int ga  = in0 + col * LSEQ + 4 * lo8;
        sud[col * 17 + lo8]     = pack8(*(const int4*)(u  + ga));
        sud[col * 17 + 8 + lo8] = pack8(*(const int4*)(dt + ga));
    }
#pragma unroll
    for (int j2 = 0; j2 < 2; ++j2) {
        const int n = nB0 + 8 * j2;
        tB[kB * 20 + n] = (float)Bm[(bb * NST + n) * LSEQ + cg * LC + kB];
    }
    __syncthreads();

    float x[NST];
#pragma unroll
    for (int n = 0; n < NST; ++n) x[n] = 0.f;
    float S = 0.f;

    const signed char* sc = (const signed char*)sud;
#pragma unroll 4
    for (int k = 0; k < LC; ++k) {
        const float uf    = (float)sc[bcol + k] * u_s;
        const float delta = softplus_f((float)sc[bcol + 32 + k] * dt_s + dtb);
        const float w     = delta * uf * B_s;
        S += delta;
        const float* bt = &tB[k * 20];
        STEP4B(0, bt); STEP4B(1, bt); STEP4B(2, bt); STEP4B(3, bt);
    }

    Sbuf[cg * SCANS + scan] = S;
    float4* Xo = (float4*)(Xbuf + (cg * SCANS + scan) * NST);
#pragma unroll
    for (int q = 0; q < 4; ++q)
        Xo[q] = make_float4(x[4*q], x[4*q+1], x[4*q+2], x[4*q+3]);
}

// ---------------- Combine: fold summaries, write init states in-place ----------------
__global__ __launch_bounds__(256) void qs_combine(
    const int* __restrict__ A_log, const float* __restrict__ A_sp,
    const float* __restrict__ Sbuf, float* __restrict__ Xbuf)
{
    const int idx  = blockIdx.x * 256 + threadIdx.x;   // flat (scan, n)
    const int scan = idx >> 4, n = idx & 15;
    const int d    = scan & (DIM - 1);
    const float A2 = -__builtin_amdgcn_exp2f(
        (float)A_log[d * NST + n] * ((*A_sp) * LOG2E)) * LOG2E;
    float x = 0.f;
#pragma unroll 8
    for (int c = 0; c < K; ++c) {
        const int off = c * (SCANS * NST) + idx;
        const float Xe = Xbuf[off];
        const float P  = __builtin_amdgcn_exp2f(A2 * Sbuf[c * SCANS + scan]);
        Xbuf[off] = x;                                  // init state for chunk c
        x = __builtin_fmaf(P, x, Xe);
    }
}

// ---------------- Phase 2: rerun with true init, emit output ----------------
__global__ __launch_bounds__(256, 4) void qs_phase2(
    const int* __restrict__ u,  const int* __restrict__ dt,
    const int* __restrict__ Bm, const int* __restrict__ Cm,
    const int* __restrict__ z,  const int* __restrict__ A_log,
    const int* __restrict__ Dv, const int* __restrict__ dt_bias,
    const float* __restrict__ u_sp,  const float* __restrict__ dt_sp,
    const float* __restrict__ A_sp,  const float* __restrict__ B_sp,
    const float* __restrict__ C_sp,  const float* __restrict__ z_sp,
    const float* __restrict__ D_sp,  const float* __restrict__ dtb_sp,
    const float* __restrict__ XI, float* __restrict__ out)
{
    const int tid = threadIdx.x;
    const int cg  = blockIdx.x >> 5;
    const int sg  = blockIdx.x & 31;
    const int scan = sg * SPB + tid;
    const int d  = scan & (DIM - 1);
    const int bb = sg >> 4;

    // per col: u 8w | dt 8w | z 8w | pad 1w  (stride 25 words, gcd(25,32)=1)
    __shared__ int   suz[256 * 25];
    __shared__ float tB[LC * 20];
    __shared__ float tC[LC * 20];

    const float u_s = *u_sp, dt_s = *dt_sp, A_s = *A_sp, B_s = *B_sp;
    const float C_s = *C_sp, z_s  = *z_sp,  D_s = *D_sp, dtb_s = *dtb_sp;
    LOAD_A2();
    const float dtb = (float)dt_bias[d] * dtb_s;
    const float Dd  = (float)Dv[d] * D_s;

    float x[NST];
    {
        const float4* xi = (const float4*)(XI + (cg * SCANS + scan) * NST);
        const float4 x0 = xi[0], x1 = xi[1], x2 = xi[2], x3 = xi[3];
        x[0]=x0.x; x[1]=x0.y; x[2]=x0.z; x[3]=x0.w;
        x[4]=x1.x; x[5]=x1.y; x[6]=x1.z; x[7]=x1.w;
        x[8]=x2.x; x[9]=x2.y; x[10]=x2.z; x[11]=x2.w;
        x[12]=x3.x; x[13]=x3.y; x[14]=x3.z; x[15]=x3.w;
    }

    const int lc8 = tid >> 3, lo8 = tid & 7;
    const int in0 = sg * SPB * LSEQ + cg * LC;
    const int kB  = tid & 31, nB0 = tid >> 5;
    const int bcol = tid * 100;
    const int ob   = scan * LSEQ + cg * LC;    // own output row-chunk base

    // stage the whole chunk: each col = one full 128B line per array
#pragma unroll
    for (int p = 0; p < 8; ++p) {
        const int col = p * 32 + lc8;
        const int ga  = in0 + col * LSEQ + 4 * lo8;
        suz[col * 25 + lo8]      = pack8(*(const int4*)(u  + ga));
        suz[col * 25 + 8 + lo8]  = pack8(*(const int4*)(dt + ga));
        suz[col * 25 + 16 + lo8] = pack8(*(const int4*)(z  + ga));
    }
#pragma unroll
    for (int j2 = 0; j2 < 2; ++j2) {
        const int n  = nB0 + 8 * j2;
        const int gr = (bb * NST + n) * LSEQ + cg * LC + kB;
        tB[kB * 20 + n] = (float)Bm[gr];
        tC[kB * 20 + n] = (float)Cm[gr];
    }
    __syncthreads();

    const signed char* sc = (const signed char*)suz;
    float ya[16];                              // 64B sector buffer, burst every 16 k
#pragma unroll 4
    for (int k = 0; k < LC; ++k) {
        const float uf    = (float)sc[bcol + k] * u_s;
        const float delta = softplus_f((float)sc[bcol + 32 + k] * dt_s + dtb);
        const float w     = delta * uf * B_s;
        const float zf    = (float)sc[bcol + 64 + k] * z_s;
        const float gate  = zf * __builtin_amdgcn_rcpf(
                                1.f + __builtin_amdgcn_exp2f(-zf * LOG2E));
        const float* bt = &tB[k * 20];
        const float* ct = &tC[k * 20];
        float y = 0.f;
        STEP4(0, bt, ct); STEP4(1, bt, ct); STEP4(2, bt, ct); STEP4(3, bt, ct);
        ya[k & 15] = __builtin_fmaf(y, C_s, Dd * uf) * gate;
        if ((k & 15) == 15) {                  // 4 back-to-back float4 stores:
            float* ob2 = out + ob + (k - 15);  // one fully-dirty 64B sector
#pragma unroll
            for (int q = 0; q < 4; ++q)
                *(float4*)(ob2 + 4 * q) =
                    make_float4(ya[4*q], ya[4*q+1], ya[4*q+2], ya[4*q+3]);
        }
    }
}

extern "C" void kernel_launch(void* const* d_in, const int* in_sizes, int n_in,
                              void* d_out, int out_size, void* d_ws, size_t ws_size,
                              hipStream_t stream) {
    const int* u   = (const int*)d_in[0];
    const int* dt  = (const int*)d_in[1];
    const int* Bm  = (const int*)d_in[2];
    const int* Cm  = (const int*)d_in[3];
    const int* z   = (const int*)d_in[4];
    const int* Al  = (const int*)d_in[5];
    const int* Dv  = (const int*)d_in[6];
    const int* dtb = (const int*)d_in[7];
    const float* u_sp = (const float*)d_in[8],  * dt_sp = (const float*)d_in[9];
    const float* A_sp = (const float*)d_in[10], * B_sp  = (const float*)d_in[11];
    const float* C_sp = (const float*)d_in[12], * z_sp  = (const float*)d_in[13];
    const float* D_sp = (const float*)d_in[14], * dtb_sp= (const float*)d_in[15];

    float* Xbuf = (float*)d_ws;                          // K*SCANS*NST f32 = 33.6 MiB
    float* Sbuf = Xbuf + (size_t)K * SCANS * NST;        // K*SCANS f32 = 2.1 MiB

    dim3 blk(256);
    qs_phase1<<<dim3(K * NSG), blk, 0, stream>>>(u, dt, Bm, Al, dtb,
        u_sp, dt_sp, A_sp, B_sp, dtb_sp, Sbuf, Xbuf);
    qs_combine<<<dim3(SCANS * NST / 256), blk, 0, stream>>>(Al, A_sp, Sbuf, Xbuf);
    qs_phase2<<<dim3(K * NSG), blk, 0, stream>>>(u, dt, Bm, Cm, z, Al, Dv, dtb,
        u_sp, dt_sp, A_sp, B_sp, C_sp, z_sp, D_sp, dtb_sp, Xbuf, (float*)d_out);
}